// Round 1
// baseline (370.346 us; speedup 1.0000x reference)
//
#include <hip/hip_runtime.h>

// Problem constants: B=1, T=4096, C=512, H=8, HS=64
#define T_ 4096
#define C_ 512
#define H_ 8
#define HS_ 64

typedef __attribute__((ext_vector_type(8))) short s16x8;   // 8 x bf16 bits
typedef __attribute__((ext_vector_type(4))) float f32x4;

__device__ __forceinline__ float bf2f(short u) {
    union { float f; unsigned int i; } v;
    v.i = ((unsigned int)(unsigned short)u) << 16;
    return v.f;
}
__device__ __forceinline__ short f2bf(float f) {
    union { float f; unsigned int i; } v;
    v.f = f;
    unsigned int r = (v.i + 0x7FFFu + ((v.i >> 16) & 1u)) >> 16;
    return (short)r;
}

// ---------------- f32 -> bf16 convert (4 elems/thread) ----------------
__global__ void cvt_kernel(const float* __restrict__ in, short* __restrict__ out, int n4) {
    int i = blockIdx.x * blockDim.x + threadIdx.x;
    if (i < n4) {
        float4 v = ((const float4*)in)[i];
        short4 o;
        o.x = f2bf(v.x); o.y = f2bf(v.y); o.z = f2bf(v.z); o.w = f2bf(v.w);
        ((short4*)out)[i] = o;
    }
}

// ---------------- GEMM: C[m][n] = sum_k A[m][k] * B[n][k] ----------------
// A: M x K row-major bf16, B: N x K row-major bf16 (i.e. B^T layout).
// 128x128 tile, BK=64, 256 threads (4 waves in 2x2), each wave 64x64.
template <int OUT_BF16>
__global__ __launch_bounds__(256) void gemm_bt(const short* __restrict__ A,
                                               const short* __restrict__ B,
                                               void* __restrict__ Cv,
                                               int M, int N, int K) {
    __shared__ __align__(16) short As[128][72];
    __shared__ __align__(16) short Bs[128][72];
    int bn = blockIdx.x, bm = blockIdx.y;
    int tid = threadIdx.x;
    int lane = tid & 63, w = tid >> 6;
    int wr = w >> 1, wc = w & 1;
    int lr = lane & 15, lg = lane >> 4;

    f32x4 acc[4][4];
#pragma unroll
    for (int m = 0; m < 4; ++m)
#pragma unroll
        for (int n = 0; n < 4; ++n) acc[m][n] = f32x4{0.f, 0.f, 0.f, 0.f};

    const short* Ab = A + (size_t)bm * 128 * K;
    const short* Bb = B + (size_t)bn * 128 * K;
    int r0 = tid >> 3, c0 = (tid & 7) * 8;

    for (int k0 = 0; k0 < K; k0 += 64) {
#pragma unroll
        for (int it = 0; it < 4; ++it) {
            int r = it * 32 + r0;
            *(s16x8*)&As[r][c0] = *(const s16x8*)(Ab + (size_t)r * K + k0 + c0);
            *(s16x8*)&Bs[r][c0] = *(const s16x8*)(Bb + (size_t)r * K + k0 + c0);
        }
        __syncthreads();
#pragma unroll
        for (int kk = 0; kk < 64; kk += 32) {
            s16x8 af[4], bf[4];
#pragma unroll
            for (int m = 0; m < 4; ++m)
                af[m] = *(const s16x8*)&As[wr * 64 + m * 16 + lr][kk + lg * 8];
#pragma unroll
            for (int n = 0; n < 4; ++n)
                bf[n] = *(const s16x8*)&Bs[wc * 64 + n * 16 + lr][kk + lg * 8];
#pragma unroll
            for (int m = 0; m < 4; ++m)
#pragma unroll
                for (int n = 0; n < 4; ++n)
                    acc[m][n] = __builtin_amdgcn_mfma_f32_16x16x32_bf16(af[m], bf[n], acc[m][n], 0, 0, 0);
        }
        __syncthreads();
    }

#pragma unroll
    for (int m = 0; m < 4; ++m) {
        int row = bm * 128 + wr * 64 + m * 16 + lg * 4;
#pragma unroll
        for (int n = 0; n < 4; ++n) {
            int col = bn * 128 + wc * 64 + n * 16 + lr;
#pragma unroll
            for (int i = 0; i < 4; ++i) {
                size_t idx = (size_t)(row + i) * N + col;
                if (OUT_BF16) ((short*)Cv)[idx] = f2bf(acc[m][n][i]);
                else          ((float*)Cv)[idx] = acc[m][n][i];
            }
        }
    }
}

// ---------------- RoPE + scatter q,k into [H][T][HS] (q pre-scaled) ----------------
__global__ void rope_scatter(const short* __restrict__ qkv, const float* __restrict__ rope,
                             short* __restrict__ q, short* __restrict__ k) {
    int g = blockIdx.x * 256 + threadIdx.x;   // T*H*32 threads
    int d2 = g & 31;
    int h = (g >> 5) & 7;
    int t = g >> 8;
    const short* row = qkv + (size_t)t * (3 * C_);
    float cs = rope[t * 64 + d2 * 2];
    float sn = rope[t * 64 + d2 * 2 + 1];
    int ci = h * 64 + d2 * 2;
    float qe = bf2f(row[ci]),          qo = bf2f(row[ci + 1]);
    float ke = bf2f(row[C_ + ci]),     ko = bf2f(row[C_ + ci + 1]);
    float qr = qe * cs - qo * sn, qi = qo * cs + qe * sn;
    float kr = ke * cs - ko * sn, ki = ko * cs + ke * sn;
    size_t o = ((size_t)h * T_ + t) * HS_ + d2 * 2;
    q[o]     = f2bf(qr * 0.125f);   // fold softmax scale 1/sqrt(64) into q
    q[o + 1] = f2bf(qi * 0.125f);
    k[o]     = f2bf(kr);
    k[o + 1] = f2bf(ki);
}

// ---------------- V transpose: qkv v-part -> vt[H][HS][T] ----------------
__global__ void vtrans(const short* __restrict__ qkv, short* __restrict__ vt) {
    __shared__ short tile[64][72];
    int bt = blockIdx.x, h = blockIdx.y;
    int tid = threadIdx.x;
#pragma unroll
    for (int it = 0; it < 16; ++it) {
        int idx = it * 256 + tid;
        int dd = idx & 63, tt = idx >> 6;
        tile[tt][dd] = qkv[(size_t)(bt * 64 + tt) * (3 * C_) + 2 * C_ + h * 64 + dd];
    }
    __syncthreads();
#pragma unroll
    for (int it = 0; it < 16; ++it) {
        int idx = it * 256 + tid;
        int tt = idx & 63, dd = idx >> 6;
        vt[((size_t)h * HS_ + dd) * T_ + bt * 64 + tt] = tile[tt][dd];
    }
}

// ---------------- Flash attention: 1 block = 64 q-rows x 1 head, 4 waves ----------------
__global__ __launch_bounds__(256) void attn_kernel(const short* __restrict__ q,
                                                   const short* __restrict__ k,
                                                   const short* __restrict__ vt,
                                                   short* __restrict__ y) {
    __shared__ __align__(16) short P[4][16][72];
    int h = blockIdx.y;
    int qb = gridDim.x - 1 - blockIdx.x;   // long blocks first
    int tid = threadIdx.x;
    int w = tid >> 6, lane = tid & 63;
    int lr = lane & 15, lg = lane >> 4;
    int qrow0 = qb * 64 + w * 16;

    const short* qp = q + ((size_t)h * T_ + qrow0 + lr) * HS_ + lg * 8;
    s16x8 aq0 = *(const s16x8*)qp;
    s16x8 aq1 = *(const s16x8*)(qp + 32);

    f32x4 yac[4];
#pragma unroll
    for (int n = 0; n < 4; ++n) yac[n] = f32x4{0.f, 0.f, 0.f, 0.f};
    float m_[4] = {-1e30f, -1e30f, -1e30f, -1e30f};
    float l_[4] = {0.f, 0.f, 0.f, 0.f};

    int nkt = (qrow0 + 15) / 64 + 1;
    for (int kt = 0; kt < nkt; ++kt) {
        int kc0 = kt * 64;
        bool domask = (kc0 + 63) > qrow0;
        f32x4 sf[4];
#pragma unroll
        for (int c = 0; c < 4; ++c) {
            int kcol = kc0 + c * 16 + lr;
            const short* kp = k + ((size_t)h * T_ + kcol) * HS_ + lg * 8;
            s16x8 b0 = *(const s16x8*)kp;
            s16x8 b1 = *(const s16x8*)(kp + 32);
            f32x4 s = f32x4{0.f, 0.f, 0.f, 0.f};
            s = __builtin_amdgcn_mfma_f32_16x16x32_bf16(aq0, b0, s, 0, 0, 0);
            s = __builtin_amdgcn_mfma_f32_16x16x32_bf16(aq1, b1, s, 0, 0, 0);
            if (domask) {
#pragma unroll
                for (int i = 0; i < 4; ++i)
                    if (kcol > qrow0 + lg * 4 + i) s[i] = -1e30f;
            }
            sf[c] = s;
        }
        // row max over 64 cols (4 frags in-register, then 16-lane butterfly)
        float rm[4];
#pragma unroll
        for (int i = 0; i < 4; ++i)
            rm[i] = fmaxf(fmaxf(sf[0][i], sf[1][i]), fmaxf(sf[2][i], sf[3][i]));
#pragma unroll
        for (int off = 1; off < 16; off <<= 1)
#pragma unroll
            for (int i = 0; i < 4; ++i)
                rm[i] = fmaxf(rm[i], __shfl_xor(rm[i], off));

        float sc_[4];
#pragma unroll
        for (int i = 0; i < 4; ++i) {
            float mn = fmaxf(m_[i], rm[i]);
            sc_[i] = __expf(m_[i] - mn);
            m_[i] = mn;
        }
        f32x4 pf[4];
#pragma unroll
        for (int c = 0; c < 4; ++c)
#pragma unroll
            for (int i = 0; i < 4; ++i)
                pf[c][i] = __expf(sf[c][i] - m_[i]);
        float rs[4];
#pragma unroll
        for (int i = 0; i < 4; ++i)
            rs[i] = pf[0][i] + pf[1][i] + pf[2][i] + pf[3][i];
#pragma unroll
        for (int off = 1; off < 16; off <<= 1)
#pragma unroll
            for (int i = 0; i < 4; ++i)
                rs[i] += __shfl_xor(rs[i], off);
#pragma unroll
        for (int i = 0; i < 4; ++i) l_[i] = l_[i] * sc_[i] + rs[i];
#pragma unroll
        for (int n = 0; n < 4; ++n)
#pragma unroll
            for (int i = 0; i < 4; ++i) yac[n][i] *= sc_[i];

        // stage P (bf16) into this wave's LDS region, re-read as A-fragment
#pragma unroll
        for (int c = 0; c < 4; ++c)
#pragma unroll
            for (int i = 0; i < 4; ++i)
                P[w][lg * 4 + i][c * 16 + lr] = f2bf(pf[c][i]);
        s16x8 ap0 = *(const s16x8*)&P[w][lr][lg * 8];
        s16x8 ap1 = *(const s16x8*)&P[w][lr][32 + lg * 8];

#pragma unroll
        for (int n = 0; n < 4; ++n) {
            const short* vp = vt + ((size_t)h * HS_ + n * 16 + lr) * T_ + kc0 + lg * 8;
            s16x8 v0 = *(const s16x8*)vp;
            s16x8 v1 = *(const s16x8*)(vp + 32);
            yac[n] = __builtin_amdgcn_mfma_f32_16x16x32_bf16(ap0, v0, yac[n], 0, 0, 0);
            yac[n] = __builtin_amdgcn_mfma_f32_16x16x32_bf16(ap1, v1, yac[n], 0, 0, 0);
        }
    }

    float inv_l[4];
#pragma unroll
    for (int i = 0; i < 4; ++i) inv_l[i] = 1.f / l_[i];
#pragma unroll
    for (int n = 0; n < 4; ++n)
#pragma unroll
        for (int i = 0; i < 4; ++i)
            y[(size_t)(qrow0 + lg * 4 + i) * C_ + h * 64 + n * 16 + lr] = f2bf(yac[n][i] * inv_l[i]);
}

// ---------------- launch ----------------
extern "C" void kernel_launch(void* const* d_in, const int* in_sizes, int n_in,
                              void* d_out, int out_size, void* d_ws, size_t ws_size,
                              hipStream_t stream) {
    const float* x    = (const float*)d_in[0];
    const float* rope = (const float*)d_in[1];
    // d_in[2] = mask (bool) — causality handled analytically
    const float* Wa   = (const float*)d_in[3];
    const float* Wp   = (const float*)d_in[4];
    float* out = (float*)d_out;

    short* ws   = (short*)d_ws;
    short* xb   = ws;                    // 4096*512        = 2097152
    short* wab  = xb + 2097152;          // 1536*512        =  786432
    short* wpb  = wab + 786432;          // 512*512         =  262144
    short* qkvb = wpb + 262144;          // 4096*1536       = 6291456
    short* qws  = qkvb + 6291456;        // 8*4096*64       = 2097152
    short* kws  = qws + 2097152;
    short* vtws = kws + 2097152;
    short* yws  = vtws + 2097152;        // 4096*512
    // total: ~34 MiB of ws

    cvt_kernel<<<2048, 256, 0, stream>>>(x,  xb,  524288);
    cvt_kernel<<<768,  256, 0, stream>>>(Wa, wab, 196608);
    cvt_kernel<<<256,  256, 0, stream>>>(Wp, wpb, 65536);

    gemm_bt<1><<<dim3(12, 32), 256, 0, stream>>>(xb, wab, qkvb, 4096, 1536, 512);

    rope_scatter<<<4096, 256, 0, stream>>>(qkvb, rope, qws, kws);
    vtrans<<<dim3(64, 8), 256, 0, stream>>>(qkvb, vtws);

    attn_kernel<<<dim3(64, 8), 256, 0, stream>>>(qws, kws, vtws, yws);

    gemm_bt<0><<<dim3(4, 32), 256, 0, stream>>>(yws, wpb, out, 4096, 512, 512);
}